// Round 5
// baseline (204.483 us; speedup 1.0000x reference)
//
#include <hip/hip_runtime.h>
#include <stdint.h>

// ---------------------------------------------------------------------------
// AVFusion round 5:
//  - gemm8p (FF2): m201 read distribution (12,4,8,0) + swapped-operand
//    float4 epilogue. Stage placement/vmcnt schedule identical to round 3.
//  - gemm64/uav: depth-1 prefetch (stage t+1 before reads of t, one barrier
//    + vmcnt(0) per iter) + swapped-operand ushort4 epilogue.
//  - cvtall / score_hid unchanged.
// ---------------------------------------------------------------------------

#define D_MODEL 1024
#define N_HEAD  8
#define DK      128
#define BS      16
#define NSEG    64
#define NSEN    32

typedef __attribute__((ext_vector_type(8))) __bf16 bf16x8;
typedef __attribute__((ext_vector_type(8))) unsigned short u16x8;
typedef __attribute__((ext_vector_type(4))) float f32x4;

__device__ __forceinline__ float bf2f(unsigned short b) {
  union { unsigned int u; float f; } x; x.u = ((unsigned int)b) << 16; return x.f;
}
__device__ __forceinline__ unsigned short f2bf(float f) {
  union { float f; unsigned int u; } x; x.f = f;
  unsigned int u = x.u;
  unsigned int r = (u + 0x7fffu + ((u >> 16) & 1u)) >> 16;  // RNE
  return (unsigned short)r;
}

// async global->LDS, 16B per lane
__device__ __forceinline__ void g2l16(const void* g, void* l) {
  __builtin_amdgcn_global_load_lds(
      (const __attribute__((address_space(1))) void*)g,
      (__attribute__((address_space(3))) void*)l, 16, 0, 0);
}

// ===================== fused fp32->bf16 convert (11 tensors) ===============
struct CvtB { const float* s[11]; unsigned short* d[11]; int n4[11]; };
__global__ __launch_bounds__(256)
void cvtall_kernel(CvtB p) {
  const int z = blockIdx.y;
  const int i = blockIdx.x * 256 + threadIdx.x;
  if (i >= p.n4[z]) return;
  float4 v = reinterpret_cast<const float4*>(p.s[z])[i];
  ushort4 o;
  o.x = f2bf(v.x); o.y = f2bf(v.y); o.z = f2bf(v.z); o.w = f2bf(v.w);
  reinterpret_cast<ushort4*>(p.d[z])[i] = o;
}

// ===================== batched 64x128-tile GEMM (prefetched) ===============
// C[M,1024] = A[M,1024] @ B[1024,1024]^T + bias (bf16 out). Up to 3 segments.
// BM=64, BN=128, BK=32, 4 waves. Depth-1 prefetch: stage(t+1) -> buf^1 before
// reading buf; lgkm(reads)->MFMA->vmcnt(0)->barrier. Reads retire before the
// barrier, so next iter's stage into buf is race-free with ONE barrier/iter.
struct GSeg { const unsigned short* A; const unsigned short* B;
              const float* bias; unsigned short* C; };
struct GBatch { GSeg s[3]; int end[3]; };

__global__ __launch_bounds__(256)
void gemm64_bt(GBatch gb) {
  __shared__ __align__(16) unsigned short lA[2][64 * 32];
  __shared__ __align__(16) unsigned short lB[2][128 * 32];

  const int nwg = gridDim.x;                 // multiple of 8
  const int sw = (blockIdx.x & 7) * (nwg >> 3) + (blockIdx.x >> 3);
  int sgi = 0, base = 0;
  if (sw >= gb.end[0]) { sgi = 1; base = gb.end[0]; }
  if (sw >= gb.end[1]) { sgi = 2; base = gb.end[1]; }
  const GSeg sg = gb.s[sgi];
  const int st = sw - base;
  const int m0 = (st >> 3) * 64, n0 = (st & 7) * 128;

  const int t = threadIdx.x;
  const int lane = t & 63, w = t >> 6;
  const int fr = lane & 15, kg = lane >> 4;

  f32x4 acc[2][4] = {};   // [ni][mi], swapped-operand layout

  const int r  = t >> 2;            // 0..63
  const int c8 = (t & 3) * 8;
  const unsigned short* ga  = sg.A + (size_t)(m0 + r) * 1024 + c8;
  const unsigned short* gbp = sg.B + (size_t)(n0 + r) * 1024 + c8;

  auto stage = [&](int buf, int k0) {
    g2l16(ga + k0,              &lA[buf][t * 8]);
    g2l16(gbp + k0,             &lB[buf][t * 8]);
    g2l16(gbp + k0 + 64 * 1024, &lB[buf][2048 + t * 8]);
  };

  stage(0, 0);
  asm volatile("s_waitcnt vmcnt(0)" ::: "memory");
  __syncthreads();

  for (int k0 = 0; k0 < 1024; k0 += 32) {
    const int buf = (k0 >> 5) & 1;
    if (k0 + 32 < 1024) stage(buf ^ 1, k0 + 32);

    u16x8 af[4], bf[2];
#pragma unroll
    for (int mi = 0; mi < 4; ++mi)
      af[mi] = *reinterpret_cast<const u16x8*>(&lA[buf][(mi * 16 + fr) * 32 + kg * 8]);
#pragma unroll
    for (int ni = 0; ni < 2; ++ni)
      bf[ni] = *reinterpret_cast<const u16x8*>(&lB[buf][(w * 32 + ni * 16 + fr) * 32 + kg * 8]);
#pragma unroll
    for (int ni = 0; ni < 2; ++ni)
#pragma unroll
      for (int mi = 0; mi < 4; ++mi)
        acc[ni][mi] = __builtin_amdgcn_mfma_f32_16x16x32_bf16(
            __builtin_bit_cast(bf16x8, bf[ni]), __builtin_bit_cast(bf16x8, af[mi]),
            acc[ni][mi], 0, 0, 0);

    asm volatile("s_waitcnt vmcnt(0)" ::: "memory");
    __syncthreads();
  }

  // swapped D layout: row(N) = kg*4+j, col(M) = fr  -> ushort4 stores
#pragma unroll
  for (int ni = 0; ni < 2; ++ni) {
    const int gn0 = n0 + w * 32 + ni * 16 + kg * 4;
    const float4 bv = *reinterpret_cast<const float4*>(&sg.bias[gn0]);
#pragma unroll
    for (int mi = 0; mi < 4; ++mi) {
      const int gm = m0 + mi * 16 + fr;
      ushort4 o;
      o.x = f2bf(acc[ni][mi][0] + bv.x);
      o.y = f2bf(acc[ni][mi][1] + bv.y);
      o.z = f2bf(acc[ni][mi][2] + bv.z);
      o.w = f2bf(acc[ni][mi][3] + bv.w);
      *reinterpret_cast<ushort4*>(&sg.C[(size_t)gm * 1024 + gn0]) = o;
    }
  }
}

// ========================= 8-phase 256x256 GEMM ============================
// Round-3 schedule with (a) m201 read distribution: P1 reads A-lo+B-lo (12),
// P2 reads B-hi (4), P3 reads A-hi (8), P4 reads none; stage placement and
// vmcnt(6) schedule UNCHANGED (each slot's last read still completes >=1
// trailing-barrier before its overwrite). (b) swapped-operand MFMA so the
// epilogue stores float4 (4 consecutive n per thread).
__global__ __launch_bounds__(512, 2)
void gemm8p_bt(const unsigned short* __restrict__ A, const unsigned short* __restrict__ B,
               const float* __restrict__ bias, float* __restrict__ C,
               int M, int N, int K, int nbx) {
  __shared__ __align__(16) unsigned short lds[2][2][256][64];

  const int nwg = gridDim.x;
  const int sw = (blockIdx.x & 7) * (nwg >> 3) + (blockIdx.x >> 3);
  const int m0 = (sw / nbx) * 256, n0 = (sw % nbx) * 256;

  const int T = threadIdx.x;
  const int lane = T & 63, wave = T >> 6;
  const int wr = wave >> 2, wc = wave & 3;
  const int fr = lane & 15, kg = lane >> 4;
  const int NT = K >> 6;

  const int sgs = (T & 7) ^ ((T >> 3) & 7);
  int grA[2][2], grB[2][2];
#pragma unroll
  for (int mh = 0; mh < 2; ++mh)
#pragma unroll
    for (int c = 0; c < 2; ++c) {
      int l = mh * 128 + c * 64 + (T >> 3);
      grA[mh][c] = ((l >> 6) & 1) * 128 + (l >> 7) * 64 + (l & 63);
      grB[mh][c] = ((l >> 5) & 3) * 64  + (l >> 7) * 32 + (l & 31);
    }
  const unsigned short* Abase = A + (size_t)m0 * K + sgs * 8;
  const unsigned short* Bbase = B + (size_t)n0 * K + sgs * 8;
  char* ldsc = (char*)&lds[0][0][0][0];

  auto stageA = [&](int buf, int mh, int t) {
#pragma unroll
    for (int c = 0; c < 2; ++c)
      g2l16(Abase + (size_t)grA[mh][c] * K + t * 64,
            ldsc + ((size_t)buf * 65536) + (mh * 128 + c * 64) * 128 + T * 16);
  };
  auto stageB = [&](int buf, int nh, int t) {
#pragma unroll
    for (int c = 0; c < 2; ++c)
      g2l16(Bbase + (size_t)grB[nh][c] * K + t * 64,
            ldsc + ((size_t)buf * 65536) + 32768 + (nh * 128 + c * 64) * 128 + T * 16);
  };

  int koff[2];
#pragma unroll
  for (int kk = 0; kk < 2; ++kk) koff[kk] = ((kk * 4 + kg) ^ (fr & 7)) * 16;
  int lrA[8], lrB[4];
#pragma unroll
  for (int mi = 0; mi < 8; ++mi) lrA[mi] = ((mi >> 2) * 128 + wr * 64 + (mi & 3) * 16 + fr) * 128;
#pragma unroll
  for (int ni = 0; ni < 4; ++ni) lrB[ni] = ((ni >> 1) * 128 + wc * 32 + (ni & 1) * 16 + fr) * 128;

  auto rdA = [&](int buf, int mi, int kk) -> u16x8 {
    return *reinterpret_cast<const u16x8*>(ldsc + (size_t)buf * 65536 + lrA[mi] + koff[kk]);
  };
  auto rdB = [&](int buf, int ni, int kk) -> u16x8 {
    return *reinterpret_cast<const u16x8*>(ldsc + (size_t)buf * 65536 + 32768 + lrB[ni] + koff[kk]);
  };

  f32x4 acc[4][8] = {};   // [ni][mi], swapped-operand layout

  stageA(0, 0, 0); stageB(0, 0, 0); stageA(0, 1, 0); stageB(0, 1, 0);
  if (NT > 1) { stageA(1, 0, 1); stageB(1, 0, 1); stageA(1, 1, 1); }
  asm volatile("s_waitcnt vmcnt(6)" ::: "memory");
  __builtin_amdgcn_s_barrier();

  u16x8 af0[4][2], af1[4][2], bf0[2][2], bf1[2][2];

  for (int t = 0; t < NT; ++t) {
    const int buf = t & 1;
    const bool st1 = (t + 1 < NT), st2 = (t + 2 < NT);

    // ---- P1: read A-lo(8) + B-lo(4); stage B-hi(t+1)->buf^1; MFMA Q1 ----
#pragma unroll
    for (int mi = 0; mi < 4; ++mi)
#pragma unroll
      for (int kk = 0; kk < 2; ++kk) af0[mi][kk] = rdA(buf, mi, kk);
#pragma unroll
    for (int ni = 0; ni < 2; ++ni)
#pragma unroll
      for (int kk = 0; kk < 2; ++kk) bf0[ni][kk] = rdB(buf, ni, kk);
    if (st1) stageB(buf ^ 1, 1, t + 1);
    __builtin_amdgcn_s_barrier();
    asm volatile("s_waitcnt lgkmcnt(0)" ::: "memory");
    __builtin_amdgcn_sched_barrier(0);
    __builtin_amdgcn_s_setprio(1);
#pragma unroll
    for (int ni = 0; ni < 2; ++ni)
#pragma unroll
      for (int mi = 0; mi < 4; ++mi)
#pragma unroll
        for (int kk = 0; kk < 2; ++kk)
          acc[ni][mi] = __builtin_amdgcn_mfma_f32_16x16x32_bf16(
              __builtin_bit_cast(bf16x8, bf0[ni][kk]), __builtin_bit_cast(bf16x8, af0[mi][kk]),
              acc[ni][mi], 0, 0, 0);
    __builtin_amdgcn_s_setprio(0);
    __builtin_amdgcn_s_barrier();

    // ---- P2: read B-hi(4); stage A-lo(t+2)->buf; MFMA Q2 (af0 x bf1) ----
#pragma unroll
    for (int ni = 0; ni < 2; ++ni)
#pragma unroll
      for (int kk = 0; kk < 2; ++kk) bf1[ni][kk] = rdB(buf, ni + 2, kk);
    if (st2) stageA(buf, 0, t + 2);
    __builtin_amdgcn_s_barrier();
    asm volatile("s_waitcnt lgkmcnt(0)" ::: "memory");
    __builtin_amdgcn_sched_barrier(0);
    __builtin_amdgcn_s_setprio(1);
#pragma unroll
    for (int ni = 0; ni < 2; ++ni)
#pragma unroll
      for (int mi = 0; mi < 4; ++mi)
#pragma unroll
        for (int kk = 0; kk < 2; ++kk)
          acc[ni + 2][mi] = __builtin_amdgcn_mfma_f32_16x16x32_bf16(
              __builtin_bit_cast(bf16x8, bf1[ni][kk]), __builtin_bit_cast(bf16x8, af0[mi][kk]),
              acc[ni + 2][mi], 0, 0, 0);
    __builtin_amdgcn_s_setprio(0);
    __builtin_amdgcn_s_barrier();

    // ---- P3: read A-hi(8); stage B-lo(t+2)->buf; MFMA Q3 (af1 x bf1) ----
#pragma unroll
    for (int mi = 0; mi < 4; ++mi)
#pragma unroll
      for (int kk = 0; kk < 2; ++kk) af1[mi][kk] = rdA(buf, mi + 4, kk);
    if (st2) stageB(buf, 0, t + 2);
    __builtin_amdgcn_s_barrier();
    asm volatile("s_waitcnt lgkmcnt(0)" ::: "memory");
    __builtin_amdgcn_sched_barrier(0);
    __builtin_amdgcn_s_setprio(1);
#pragma unroll
    for (int ni = 0; ni < 2; ++ni)
#pragma unroll
      for (int mi = 0; mi < 4; ++mi)
#pragma unroll
        for (int kk = 0; kk < 2; ++kk)
          acc[ni + 2][mi + 4] = __builtin_amdgcn_mfma_f32_16x16x32_bf16(
              __builtin_bit_cast(bf16x8, bf1[ni][kk]), __builtin_bit_cast(bf16x8, af1[mi][kk]),
              acc[ni + 2][mi + 4], 0, 0, 0);
    __builtin_amdgcn_s_setprio(0);
    __builtin_amdgcn_s_barrier();

    // ---- P4: no reads; stage A-hi(t+2)->buf; MFMA Q4 (af1 x bf0); vmcnt ----
    if (st2) stageA(buf, 1, t + 2);
    __builtin_amdgcn_s_barrier();
    __builtin_amdgcn_s_setprio(1);
#pragma unroll
    for (int ni = 0; ni < 2; ++ni)
#pragma unroll
      for (int mi = 0; mi < 4; ++mi)
#pragma unroll
        for (int kk = 0; kk < 2; ++kk)
          acc[ni][mi + 4] = __builtin_amdgcn_mfma_f32_16x16x32_bf16(
              __builtin_bit_cast(bf16x8, bf0[ni][kk]), __builtin_bit_cast(bf16x8, af1[mi][kk]),
              acc[ni][mi + 4], 0, 0, 0);
    __builtin_amdgcn_s_setprio(0);
    if (st2)       asm volatile("s_waitcnt vmcnt(6)" ::: "memory");
    else if (st1)  asm volatile("s_waitcnt vmcnt(0)" ::: "memory");
    __builtin_amdgcn_s_barrier();
  }

  // swapped D layout: row(N) = kg*4+j, col(M) = fr  -> float4 stores
#pragma unroll
  for (int ni = 0; ni < 4; ++ni) {
    const int gn0 = n0 + wc * 64 + ni * 16 + kg * 4;
    const float4 bv = *reinterpret_cast<const float4*>(&bias[gn0]);
#pragma unroll
    for (int mi = 0; mi < 8; ++mi) {
      const int gm = m0 + wr * 128 + mi * 16 + fr;
      float4 o;
      o.x = acc[ni][mi][0] + bv.x;
      o.y = acc[ni][mi][1] + bv.y;
      o.z = acc[ni][mi][2] + bv.z;
      o.w = acc[ni][mi][3] + bv.w;
      *reinterpret_cast<float4*>(&C[(size_t)gm * N + gn0]) = o;
    }
  }
}

// ===================== UA/UV batched small GEMM (prefetched) ===============
__global__ __launch_bounds__(256)
void uav_gemm(const unsigned short* __restrict__ vAV, const unsigned short* __restrict__ w1,
              unsigned short* __restrict__ UAV) {
  __shared__ __align__(16) unsigned short lA[2][128 * 32];
  __shared__ __align__(16) unsigned short lB[2][128 * 32];

  const int zb = blockIdx.z;
  const int tensor = zb >> 3, h = zb & 7;
  const unsigned short* Ab = vAV + (size_t)tensor * (1024 * 1024) + h * 128;
  const unsigned short* Bb = w1 + h * 128;
  unsigned short* Cb = UAV + (size_t)tensor * (1024 * 8192) + h * 1024;

  const int t = threadIdx.x;
  const int m0 = blockIdx.y * 128, n0 = blockIdx.x * 128;
  const int lane = t & 63, wv = t >> 6;
  const int wrow = (wv >> 1) * 64, wcol = (wv & 1) * 64;
  const int fr = lane & 15, kg = lane >> 4;

  f32x4 acc[4][4] = {};   // [ni][mi], swapped-operand layout

  const int r  = t >> 2;
  const int c8 = (t & 3) * 8;
  const unsigned short* ga = Ab + (size_t)(m0 + r) * 1024 + c8;
  const unsigned short* gb = Bb + (size_t)(n0 + r) * 1024 + c8;

  auto stage = [&](int buf, int k0) {
    g2l16(ga + k0,             &lA[buf][t * 8]);
    g2l16(ga + k0 + 64 * 1024, &lA[buf][2048 + t * 8]);
    g2l16(gb + k0,             &lB[buf][t * 8]);
    g2l16(gb + k0 + 64 * 1024, &lB[buf][2048 + t * 8]);
  };

  stage(0, 0);
  asm volatile("s_waitcnt vmcnt(0)" ::: "memory");
  __syncthreads();

  for (int k0 = 0; k0 < 128; k0 += 32) {
    const int buf = (k0 >> 5) & 1;
    if (k0 + 32 < 128) stage(buf ^ 1, k0 + 32);

    u16x8 af[4], bg_[4];
#pragma unroll
    for (int mi = 0; mi < 4; ++mi)
      af[mi] = *reinterpret_cast<const u16x8*>(&lA[buf][(wrow + mi * 16 + fr) * 32 + kg * 8]);
#pragma unroll
    for (int ni = 0; ni < 4; ++ni)
      bg_[ni] = *reinterpret_cast<const u16x8*>(&lB[buf][(wcol + ni * 16 + fr) * 32 + kg * 8]);
#pragma unroll
    for (int ni = 0; ni < 4; ++ni)
#pragma unroll
      for (int mi = 0; mi < 4; ++mi)
        acc[ni][mi] = __builtin_amdgcn_mfma_f32_16x16x32_bf16(
            __builtin_bit_cast(bf16x8, bg_[ni]), __builtin_bit_cast(bf16x8, af[mi]),
            acc[ni][mi], 0, 0, 0);

    asm volatile("s_waitcnt vmcnt(0)" ::: "memory");
    __syncthreads();
  }

#pragma unroll
  for (int ni = 0; ni < 4; ++ni) {
    const int gn0 = n0 + wcol + ni * 16 + kg * 4;
#pragma unroll
    for (int mi = 0; mi < 4; ++mi) {
      const int gm = m0 + wrow + mi * 16 + fr;
      ushort4 o;
      o.x = f2bf(acc[ni][mi][0]);
      o.y = f2bf(acc[ni][mi][1]);
      o.z = f2bf(acc[ni][mi][2]);
      o.w = f2bf(acc[ni][mi][3]);
      *reinterpret_cast<ushort4*>(&Cb[(size_t)gm * 8192 + gn0]) = o;
    }
  }
}

// ============== fused score + hid assembly (one block per (b,g)) ===========
__global__ __launch_bounds__(256)
void score_hid_kernel(const unsigned short* __restrict__ q,
                      const unsigned short* __restrict__ kAV,
                      const unsigned short* __restrict__ UAV,
                      const float* __restrict__ b1,
                      unsigned short* __restrict__ hid) {
  const int bg = blockIdx.x;
  const int b = bg >> 6, g = bg & 63;
  __shared__ float sk[2][D_MODEL];
  __shared__ float pAl[NSEN][N_HEAD];
  const size_t rowA = (size_t)bg * D_MODEL;
  const size_t rowV = rowA + (size_t)BS * NSEG * D_MODEL;
  for (int i = threadIdx.x; i < D_MODEL; i += 256) {
    sk[0][i] = bf2f(kAV[rowA + i]);
    sk[1][i] = bf2f(kAV[rowV + i]);
  }
  __syncthreads();

  const int h = threadIdx.x >> 5;
  const int l = threadIdx.x & 31;
  const float scale = 0.08838834764831845f;  // 1/sqrt(128)

  for (int s = 0; s < NSEN; ++s) {
    const unsigned short* pq = q + ((size_t)(b * NSEN + s)) * D_MODEL + h * DK;
    float la = 0.f, lv = 0.f;
#pragma unroll
    for (int e = 0; e < 4; ++e) {
      int d = l + e * 32;
      float qv = bf2f(pq[d]);
      la += qv * sk[0][h * DK + d];
      lv += qv * sk[1][h * DK + d];
    }
#pragma unroll
    for (int off = 16; off; off >>= 1) {
      la += __shfl_xor(la, off, 32);
      lv += __shfl_xor(lv, off, 32);
    }
    if (l == 0) pAl[s][h] = 1.f / (1.f + __expf((lv - la) * scale));
  }
  __syncthreads();

  const int n0 = threadIdx.x * 4;
  const unsigned short* ua = UAV + (size_t)bg * 8192 + n0;
  const unsigned short* uv = ua + (size_t)1024 * 8192;

  float dU[N_HEAD][4];
  float base[4];
#pragma unroll
  for (int j = 0; j < 4; ++j) base[j] = b1[n0 + j];
#pragma unroll
  for (int hh = 0; hh < N_HEAD; ++hh) {
    ushort4 a4 = *reinterpret_cast<const ushort4*>(ua + hh * 1024);
    ushort4 v4 = *reinterpret_cast<const ushort4*>(uv + hh * 1024);
    float va[4] = {bf2f(a4.x), bf2f(a4.y), bf2f(a4.z), bf2f(a4.w)};
    float vv[4] = {bf2f(v4.x), bf2f(v4.y), bf2f(v4.z), bf2f(v4.w)};
#pragma unroll
    for (int j = 0; j < 4; ++j) { dU[hh][j] = va[j] - vv[j]; base[j] += vv[j]; }
  }

  for (int s = 0; s < NSEN; ++s) {
    float val[4] = {base[0], base[1], base[2], base[3]};
#pragma unroll
    for (int hh = 0; hh < N_HEAD; ++hh) {
      const float p = pAl[s][hh];
#pragma unroll
      for (int j = 0; j < 4; ++j) val[j] = fmaf(p, dU[hh][j], val[j]);
    }
    ushort4 o;
    o.x = f2bf(val[0] > 0.f ? val[0] : 0.f);
    o.y = f2bf(val[1] > 0.f ? val[1] : 0.f);
    o.z = f2bf(val[2] > 0.f ? val[2] : 0.f);
    o.w = f2bf(val[3] > 0.f ? val[3] : 0.f);
    size_t orow = ((size_t)(b * NSEN + s) * NSEG + g) * D_MODEL + n0;
    *reinterpret_cast<ushort4*>(hid + orow) = o;
  }
}

extern "C" void kernel_launch(void* const* d_in, const int* in_sizes, int n_in,
                              void* d_out, int out_size, void* d_ws, size_t ws_size,
                              hipStream_t stream) {
  const float* A  = (const float*)d_in[0];
  const float* V  = (const float*)d_in[1];
  const float* S  = (const float*)d_in[2];
  const float* wA = (const float*)d_in[3];  const float* bA = (const float*)d_in[4];
  const float* wV = (const float*)d_in[5];  const float* bV = (const float*)d_in[6];
  const float* wS = (const float*)d_in[7];  const float* bS = (const float*)d_in[8];
  const float* wq = (const float*)d_in[9];  const float* bq = (const float*)d_in[10];
  const float* wk = (const float*)d_in[11]; const float* bk = (const float*)d_in[12];
  const float* wv = (const float*)d_in[13]; const float* bv = (const float*)d_in[14];
  const float* w1 = (const float*)d_in[15]; const float* b1 = (const float*)d_in[16];
  const float* w2 = (const float*)d_in[17]; const float* b2 = (const float*)d_in[18];

  const int nAV = BS * NSEG * D_MODEL;         // 1,048,576
  const int nS  = BS * NSEN * D_MODEL;         // 524,288
  const int nW  = D_MODEL * D_MODEL;           // 1,048,576
  const int nCT = BS * NSEN * NSEG * D_MODEL;  // 33,554,432
  const int nU  = 2 * 1024 * 8 * 1024;         // 16,777,216

  char* ws = (char*)d_ws;
  size_t off = 0;
  auto carve = [&](size_t elems) {
    unsigned short* p = (unsigned short*)(ws + off);
    off += elems * sizeof(unsigned short);
    return p;
  };
  unsigned short* bwA = carve(nW);
  unsigned short* bwV = carve(nW);
  unsigned short* bwS = carve(nW);
  unsigned short* bwq = carve(nW);
  unsigned short* bwk = carve(nW);
  unsigned short* bwv = carve(nW);
  unsigned short* bw1 = carve(nW);
  unsigned short* bw2 = carve(nW);
  unsigned short* xA  = carve(nAV);
  unsigned short* xV  = carve(nAV);
  unsigned short* xS  = carve(nS);
  unsigned short* A1V1 = carve(2 * nAV);   // A1 rows then V1 rows
  unsigned short* S1  = carve(nS);
  unsigned short* qb  = carve(nS);
  unsigned short* kAV = carve(2 * nAV);    // kA rows then kV rows
  unsigned short* vAV = carve(2 * nAV);    // vA rows then vV rows
  unsigned short* UAV = carve(nU);         // [2][1024][8][1024]
  unsigned short* hid = carve(nCT);        // 64MB
  (void)ws_size; (void)n_in; (void)in_sizes; (void)out_size;

  // 1) all fp32->bf16 converts in one launch
  CvtB cv;
  cv.s[0] = wA; cv.d[0] = bwA; cv.n4[0] = nW / 4;
  cv.s[1] = wV; cv.d[1] = bwV; cv.n4[1] = nW / 4;
  cv.s[2] = wS; cv.d[2] = bwS; cv.n4[2] = nW / 4;
  cv.s[3] = wq; cv.d[3] = bwq; cv.n4[3] = nW / 4;
  cv.s[4] = wk; cv.d[4] = bwk; cv.n4[4] = nW / 4;
  cv.s[5] = wv; cv.d[5] = bwv; cv.n4[5] = nW / 4;
  cv.s[6] = w1; cv.d[6] = bw1; cv.n4[6] = nW / 4;
  cv.s[7] = w2; cv.d[7] = bw2; cv.n4[7] = nW / 4;
  cv.s[8] = A;  cv.d[8] = xA;  cv.n4[8] = nAV / 4;
  cv.s[9] = V;  cv.d[9] = xV;  cv.n4[9] = nAV / 4;
  cv.s[10] = S; cv.d[10] = xS; cv.n4[10] = nS / 4;
  cvtall_kernel<<<dim3(1024, 11), dim3(256), 0, stream>>>(cv);

  // 2) input projections A,V,S in one batched launch (tiles: 128,128,64)
  GBatch pj;
  pj.s[0] = {xA, bwA, bA, A1V1};        pj.end[0] = 128;
  pj.s[1] = {xV, bwV, bV, A1V1 + nAV};  pj.end[1] = 256;
  pj.s[2] = {xS, bwS, bS, S1};          pj.end[2] = 320;
  gemm64_bt<<<dim3(320), 256, 0, stream>>>(pj);

  // 3) q,k,v projections in one batched launch (tiles: 64,256,256)
  GBatch qkv;
  qkv.s[0] = {S1,   bwq, bq, qb};   qkv.end[0] = 64;
  qkv.s[1] = {A1V1, bwk, bk, kAV};  qkv.end[1] = 320;
  qkv.s[2] = {A1V1, bwv, bv, vAV};  qkv.end[2] = 576;
  gemm64_bt<<<dim3(576), 256, 0, stream>>>(qkv);

  // 4) UA/UV batched small GEMMs
  uav_gemm<<<dim3(8, 8, 16), dim3(256), 0, stream>>>(vAV, bw1, UAV);

  // 5) fused scores + hid assembly
  score_hid_kernel<<<dim3(BS * NSEG), dim3(256), 0, stream>>>(qb, kAV, UAV, b1, hid);

  // 6) FF2 on the 8-phase 256^2 schedule
  gemm8p_bt<<<dim3(512), 512, 0, stream>>>(hid, bw2, b2, (float*)d_out,
                                           32768, 1024, 1024, 4);
}